// Round 4
// baseline (678.608 us; speedup 1.0000x reference)
//
#include <hip/hip_runtime.h>
#include <cstddef>

#define EPSF 1e-12f

constexpr int Bc = 16, Dc = 128, Lc = 4096, Kc = 4096;
constexpr int Nc = Bc * Lc;     // 65536
constexpr float TAU = 1e-3f;    // covers split err (~2e-5) + pack err (2*2.4e-4)
constexpr int RCAP = 32768;

typedef __attribute__((ext_vector_type(8))) short short8;
typedef __attribute__((ext_vector_type(4))) float f32x4;

__device__ __forceinline__ unsigned short f2bf(float f) {
    unsigned u = __float_as_uint(f);
    return (unsigned short)((u + 0x7fffu + ((u >> 16) & 1u)) >> 16);
}
__device__ __forceinline__ float bf2f(unsigned short u) {
    return __uint_as_float(((unsigned)u) << 16);
}
__device__ __forceinline__ float med3(float a, float b, float c) {
#if __has_builtin(__builtin_amdgcn_fmed3f)
    return __builtin_amdgcn_fmed3f(a, b, c);
#else
    return fmaxf(fminf(a, b), fminf(fmaxf(a, b), c));
#endif
}
// pack code (12b) into cleared low mantissa: one v_and_or_b32
__device__ __forceinline__ float packv(float a, unsigned code) {
    return __uint_as_float((__float_as_uint(a) & 0xFFFFF000u) | code);
}

// ---------------------------------------------------------------------------
// Codebook prep: normalize -> cbn (f32, gather/repair) and bf16-split planes
// in TRANSPOSED chunk-major layout cbhT/cblT[chunk16][code4096] (16B chunks)
// so k_argmax's global prefetch is coalesced AND its LDS staging/reads are
// conflict-free with immediate offsets. One wave per codebook row.
// ---------------------------------------------------------------------------
__global__ void k_cbprep(const float* __restrict__ emb, float* __restrict__ cbn,
                         short* __restrict__ cbhT, short* __restrict__ cblT,
                         float* __restrict__ lacc, int* __restrict__ rcnt) {
    __shared__ short rh[4][128], rl[4][128];
    const int w = threadIdx.x >> 6, lane = threadIdx.x & 63;
    const int k = (blockIdx.x << 2) + w;
    float2 v = ((const float2*)(emb + (size_t)k * Dc))[lane];
    float s = v.x * v.x + v.y * v.y;
    #pragma unroll
    for (int off = 32; off > 0; off >>= 1) s += __shfl_down(s, off);
    s = __shfl(s, 0);
    float inv = 1.f / fmaxf(sqrtf(s), EPSF);
    v.x *= inv; v.y *= inv;
    ((float2*)(cbn + (size_t)k * Dc))[lane] = v;
    unsigned short h0 = f2bf(v.x), h1 = f2bf(v.y);
    rh[w][2 * lane]     = (short)h0;
    rh[w][2 * lane + 1] = (short)h1;
    rl[w][2 * lane]     = (short)f2bf(v.x - bf2f(h0));
    rl[w][2 * lane + 1] = (short)f2bf(v.y - bf2f(h1));
    __syncthreads();
    int t = threadIdx.x;
    if (t < 64) {
        int r = t >> 4, j = t & 15;                  // row-in-block, chunk
        int kk = (blockIdx.x << 2) + r;
        *(int4*)(cbhT + j * 32768 + kk * 8) = *(const int4*)&rh[r][j * 8];
        *(int4*)(cblT + j * 32768 + kk * 8) = *(const int4*)&rl[r][j * 8];
    }
    if (blockIdx.x == 0 && threadIdx.x == 0) { *lacc = 0.f; *rcnt = 0; }
}

// ---------------------------------------------------------------------------
// MFMA argmax. 128 rows/block, 64-code tiles double-buffered in 64KB LDS,
// chunk-major planes: read addr = lane_base + (kd*4096 + ct*256) immediate.
// Fold = packed-value max/med3 (index embedded in low mantissa bits).
// ---------------------------------------------------------------------------
__global__ __launch_bounds__(256, 1)
void k_argmax(const float* __restrict__ x, const short* __restrict__ cbhT,
              const short* __restrict__ cblT, float* __restrict__ invn,
              int* __restrict__ idx_out, float* __restrict__ lossacc,
              int* __restrict__ rcnt, int* __restrict__ rlist,
              unsigned long long* __restrict__ rbest) {
    __shared__ __align__(16) char smem[65536];
    float* xt   = (float*)smem;              // [64][129] f32 (preamble overlay)
    float* invl = (float*)(smem + 33024);    // [64]      (preamble overlay)

    const int tid  = threadIdx.x;
    const int w    = tid >> 6;
    const int lane = tid & 63;
    const int m16  = lane & 15;
    const int quad = lane >> 4;
    const int n0   = blockIdx.x * 128;
    const int bI   = n0 >> 12;
    const int l0   = n0 & (Lc - 1);
    const float* xb = x + (size_t)bI * Dc * Lc;

    // ---- tile-0 prefetch, coalesced from transposed planes ----
    const int c  = tid & 63;         // code within tile
    const int jg = (tid >> 6) * 4;   // this wave's 4 chunks
    const short* pbh = cbhT + jg * 32768 + c * 8;
    const short* pbl = cblT + jg * 32768 + c * 8;
    int4 ph[4], pl[4];
    #pragma unroll
    for (int j = 0; j < 4; ++j) {
        ph[j] = *(const int4*)(pbh + j * 32768);
        pl[j] = *(const int4*)(pbl + j * 32768);
    }

    // ---- preamble: transpose+normalize x, build per-wave A fragments ----
    short8 ah[2][4], al[2][4];
    for (int h = 0; h < 2; ++h) {
        __syncthreads();
        #pragma unroll
        for (int j = 0; j < 8; ++j) {
            int fl = tid + j * 256;
            int d = fl >> 4, lq = fl & 15;
            float4 v = *(const float4*)(xb + (size_t)d * Lc + l0 + h * 64 + lq * 4);
            xt[(lq * 4 + 0) * 129 + d] = v.x;
            xt[(lq * 4 + 1) * 129 + d] = v.y;
            xt[(lq * 4 + 2) * 129 + d] = v.z;
            xt[(lq * 4 + 3) * 129 + d] = v.w;
        }
        __syncthreads();
        {   // row norms, 4 threads/row
            int row = tid >> 2, q = tid & 3;
            float s = 0.f;
            #pragma unroll
            for (int j = 0; j < 32; ++j) { float t = xt[row * 129 + q * 32 + j]; s += t * t; }
            s += __shfl_down(s, 1); s += __shfl_down(s, 2);
            if (q == 0) {
                float inv = 1.f / fmaxf(sqrtf(s), EPSF);
                invl[row] = inv;
                invn[n0 + h * 64 + row] = inv;
            }
        }
        __syncthreads();
        if ((w >> 1) == h) {   // waves 2h,2h+1 build frags for these 64 rows
            #pragma unroll
            for (int rt = 0; rt < 2; ++rt) {
                int rl = (w & 1) * 32 + rt * 16 + m16;   // A layout: m = lane&15
                float inv = invl[rl];
                #pragma unroll
                for (int kd = 0; kd < 4; ++kd) {
                    int dof = kd * 32 + quad * 8;        // k = quad*8 + j
                    short8 hh, ll;
                    #pragma unroll
                    for (int j = 0; j < 8; ++j) {
                        float xn = xt[rl * 129 + dof + j] * inv;
                        unsigned short hb = f2bf(xn);
                        hh[j] = (short)hb;
                        ll[j] = (short)f2bf(xn - bf2f(hb));
                    }
                    ah[rt][kd] = hh; al[rt][kd] = ll;
                }
            }
        }
    }
    __syncthreads();   // xt dead; B double-buffer owns the LDS

    // ---- K loop: 64 tiles of 64 codes ----
    const f32x4 fz = {0.f, 0.f, 0.f, 0.f};
    float Bb[8], Ss[8];
    #pragma unroll
    for (int i = 0; i < 8; ++i) { Bb[i] = -3.0e38f; Ss[i] = -3.0e38f; }
    unsigned kc[4];
    #pragma unroll
    for (int ctt = 0; ctt < 4; ++ctt) kc[ctt] = (unsigned)(ctt * 16 + m16);

    for (int t = 0; t < 64; ++t) {
        const int bb = (t & 1) << 15;
        char* st = smem + bb + jg * 1024 + c * 16;
        #pragma unroll
        for (int j = 0; j < 4; ++j) {          // conflict-free staging writes
            *(int4*)(st + j * 1024)         = ph[j];
            *(int4*)(st + 16384 + j * 1024) = pl[j];
        }
        __syncthreads();
        if (t < 63) {                          // coalesced prefetch of tile t+1
            int off = (t + 1) * 512;           // shorts
            #pragma unroll
            for (int j = 0; j < 4; ++j) {
                ph[j] = *(const int4*)(pbh + j * 32768 + off);
                pl[j] = *(const int4*)(pbl + j * 32768 + off);
            }
        }

        const char* rdh = smem + bb + quad * 1024 + m16 * 16;
        f32x4 acc[2][4];
        #pragma unroll
        for (int kd = 0; kd < 4; ++kd) {
            short8 bh[4], bl[4];
            #pragma unroll
            for (int ct = 0; ct < 4; ++ct) {   // immediate-offset ds_read_b128
                bh[ct] = *(const short8*)(rdh + kd * 4096 + ct * 256);
                bl[ct] = *(const short8*)(rdh + 16384 + kd * 4096 + ct * 256);
            }
            #pragma unroll
            for (int rt = 0; rt < 2; ++rt)
                #pragma unroll
                for (int ct = 0; ct < 4; ++ct)
                    acc[rt][ct] = __builtin_amdgcn_mfma_f32_16x16x32_bf16(
                        ah[rt][kd], bh[ct], (kd == 0) ? fz : acc[rt][ct], 0, 0, 0);
            #pragma unroll
            for (int rt = 0; rt < 2; ++rt)
                #pragma unroll
                for (int ct = 0; ct < 4; ++ct)
                    acc[rt][ct] = __builtin_amdgcn_mfma_f32_16x16x32_bf16(
                        ah[rt][kd], bl[ct], acc[rt][ct], 0, 0, 0);
            #pragma unroll
            for (int rt = 0; rt < 2; ++rt)
                #pragma unroll
                for (int ct = 0; ct < 4; ++ct)
                    acc[rt][ct] = __builtin_amdgcn_mfma_f32_16x16x32_bf16(
                        al[rt][kd], bh[ct], acc[rt][ct], 0, 0, 0);
        }

        // packed fold: best+second per row-slot, index in low mantissa bits
        #pragma unroll
        for (int rt = 0; rt < 2; ++rt)
            #pragma unroll
            for (int rg = 0; rg < 4; ++rg) {
                int s = rt * 4 + rg;
                float p0 = packv(acc[rt][0][rg], kc[0]);
                float p1 = packv(acc[rt][1][rg], kc[1]);
                float p2 = packv(acc[rt][2][rg], kc[2]);
                float p3 = packv(acc[rt][3][rg], kc[3]);
                float h1 = fmaxf(p0, p1), l1 = fminf(p0, p1);
                float h2 = fmaxf(p2, p3), l2 = fminf(p2, p3);
                float hi4  = fmaxf(h1, h2);
                float sec4 = med3(h1, h2, fmaxf(l1, l2));
                float ssn  = fmaxf(Ss[s], med3(Bb[s], hi4, sec4));
                Bb[s] = fmaxf(Bb[s], hi4);
                Ss[s] = ssn;
            }
        #pragma unroll
        for (int ctt = 0; ctt < 4; ++ctt) kc[ctt] += 64;
    }

    // ---- epilogue: merge the 16 col-contributor lanes per row ----
    float lossl = 0.f;
    int nflag = 0; int flagn[8]; float flagv[8];
    #pragma unroll
    for (int s = 0; s < 8; ++s) {
        int rt = s >> 2, rg = s & 3;
        float v1 = Bb[s], v2 = Ss[s];
        #pragma unroll
        for (int off = 1; off < 16; off <<= 1) {
            float ov1 = __shfl_xor(v1, off);
            float ov2 = __shfl_xor(v2, off);
            v2 = fmaxf(fmaxf(v2, ov2), fminf(v1, ov1));
            v1 = fmaxf(v1, ov1);
        }
        if (m16 == 0) {
            int n = n0 + w * 32 + rt * 16 + quad * 4 + rg;   // C row = quad*4+reg
            idx_out[n] = (int)(__float_as_uint(v1) & 0xFFFu);
            lossl += v1;
            if (v1 - v2 < TAU) { flagn[nflag] = n; flagv[nflag] = v1; ++nflag; }
        }
    }
    for (int i = 0; i < nflag; ++i) {          // rare path
        int pos = atomicAdd(rcnt, 1);
        if (pos < RCAP) { rlist[pos] = flagn[i]; rbest[pos] = 0ull; }
        (void)flagv[i];
    }
    float p = (m16 == 0) ? lossl : 0.f;
    #pragma unroll
    for (int off = 1; off < 64; off <<= 1) p += __shfl_xor(p, off);
    if (lane == 0) atomicAdd(lossacc, p);
}

// ---------------------------------------------------------------------------
// Parallel exact repair: blocks = (query-batch of 16) x (16 chunks of 256
// codes). Merge via order-preserving packed u64 atomicMax (tie -> smaller k).
// ---------------------------------------------------------------------------
__global__ __launch_bounds__(256)
void k_repair(const float* __restrict__ x, const float* __restrict__ invn,
              const float* __restrict__ cbn, const int* __restrict__ rcnt,
              const int* __restrict__ rlist, unsigned long long* __restrict__ rbest) {
    __shared__ float xs[16][128];
    int cnt = *rcnt; if (cnt > RCAP) cnt = RCAP;
    if (cnt == 0) return;
    const int nb    = (cnt + 15) >> 4;
    const int chunk = blockIdx.x & 15;
    const int tid   = threadIdx.x;
    for (int bat = blockIdx.x >> 4; bat < nb; bat += (gridDim.x >> 4)) {
        int q0 = bat << 4;
        int nq = min(16, cnt - q0);
        __syncthreads();
        for (int i = tid; i < (nq << 7); i += 256) {
            int q = i >> 7, d = i & 127;
            int n = rlist[q0 + q];
            xs[q][d] = x[(size_t)(n >> 12) * (Dc * Lc) + (size_t)d * Lc + (n & (Lc - 1))]
                       * invn[n];
        }
        __syncthreads();
        const int k = (chunk << 8) + tid;      // one code per thread
        float acc[16];
        #pragma unroll
        for (int q = 0; q < 16; ++q) acc[q] = 0.f;
        const float4* cr = (const float4*)(cbn + (size_t)k * Dc);
        #pragma unroll
        for (int half = 0; half < 2; ++half) {
            float4 cv[16];
            #pragma unroll
            for (int j = 0; j < 16; ++j) cv[j] = cr[half * 16 + j];
            #pragma unroll
            for (int q = 0; q < 16; ++q) {
                float s = 0.f;
                #pragma unroll
                for (int j = 0; j < 16; ++j) {
                    float4 xx = *(const float4*)&xs[q][half * 64 + j * 4];
                    s += cv[j].x * xx.x + cv[j].y * xx.y + cv[j].z * xx.z + cv[j].w * xx.w;
                }
                acc[q] += s;
            }
        }
        for (int q = 0; q < nq; ++q) {
            unsigned kb = __float_as_uint(acc[q]);
            kb = (kb & 0x80000000u) ? ~kb : (kb | 0x80000000u);
            unsigned long long pk =
                ((unsigned long long)kb << 32) | (unsigned)(0xFFFFFFFFu - (unsigned)k);
            #pragma unroll
            for (int off = 32; off >= 1; off >>= 1) {
                unsigned long long o = __shfl_xor(pk, off);
                pk = (o > pk) ? o : pk;
            }
            if ((tid & 63) == 0) atomicMax(&rbest[q0 + q], pk);
        }
    }
}

__global__ void k_fix(int* __restrict__ idx, const int* __restrict__ rcnt,
                      const int* __restrict__ rlist,
                      const unsigned long long* __restrict__ rbest) {
    int cnt = *rcnt; if (cnt > RCAP) cnt = RCAP;
    int i = blockIdx.x * 256 + threadIdx.x;
    if (i < cnt)
        idx[rlist[i]] = (int)(0xFFFFFFFFu - (unsigned)(rbest[i] & 0xFFFFFFFFull));
}

// ---------------------------------------------------------------------------
__global__ void k_gather(const float* __restrict__ cbn, const int* __restrict__ idx,
                         float* __restrict__ out) {
    __shared__ int sidx[64];
    int n0 = blockIdx.x << 6;
    int b  = n0 >> 12;
    int l0 = n0 & (Lc - 1);
    if (threadIdx.x < 64) sidx[threadIdx.x] = idx[n0 + threadIdx.x];
    __syncthreads();
    int t = threadIdx.x;
    #pragma unroll
    for (int i = 0; i < 32; ++i) {
        int p = t + (i << 8);
        int d = p >> 6;
        int l = p & 63;
        out[(size_t)b * Dc * Lc + (size_t)d * Lc + l0 + l] = cbn[(size_t)sidx[l] * Dc + d];
    }
}

__global__ void k_loss(const float* __restrict__ lacc, float* __restrict__ oloss) {
    *oloss = 2.0f - 2.0f * (*lacc) / (float)Nc;
}

// ---------------------------------------------------------------------------
extern "C" void kernel_launch(void* const* d_in, const int* in_sizes, int n_in,
                              void* d_out, int out_size, void* d_ws, size_t ws_size,
                              hipStream_t stream) {
    const float* x   = (const float*)d_in[0];   // [16][128][4096] fp32
    const float* emb = (const float*)d_in[1];   // [4096][128] fp32
    float* out = (float*)d_out;

    char* ws = (char*)d_ws;
    float* cbn  = (float*)ws;                                    // 2 MB
    short* cbhT = (short*)(ws + (2u << 20));                     // 1 MB [chunk][code]
    short* cblT = (short*)(ws + (3u << 20));                     // 1 MB
    float* invn = (float*)(ws + (4u << 20));                     // 256 KB
    int*   idx  = (int*)(ws + (4u << 20) + (256u << 10));        // 256 KB
    char*  b5   = ws + (4u << 20) + (512u << 10);
    float* lacc = (float*)b5;
    int*   rcnt = (int*)(b5 + 64);
    int*   rlist= (int*)(b5 + 1024);                             // 128 KB
    unsigned long long* rbest = (unsigned long long*)(b5 + 1024 + (128u << 10)); // 256 KB

    k_cbprep<<<Kc / 4,   256, 0, stream>>>(emb, cbn, cbhT, cblT, lacc, rcnt);
    k_argmax<<<Nc / 128, 256, 0, stream>>>(x, cbhT, cblT, invn, idx, lacc,
                                           rcnt, rlist, rbest);
    k_repair<<<1024,     256, 0, stream>>>(x, invn, cbn, rcnt, rlist, rbest);
    k_fix   <<<RCAP/256, 256, 0, stream>>>(idx, rcnt, rlist, rbest);
    k_gather<<<Nc / 64,  256, 0, stream>>>(cbn, idx, out);
    k_loss  <<<1, 1,     0, stream>>>(lacc, out + (size_t)Bc * Dc * Lc);
}

// Round 5
// 425.690 us; speedup vs baseline: 1.5941x; 1.5941x over previous
//
#include <hip/hip_runtime.h>
#include <cstddef>

#define EPSF 1e-12f

constexpr int Bc = 16, Dc = 128, Lc = 4096, Kc = 4096;
constexpr int Nc = Bc * Lc;     // 65536
constexpr float TAU = 1e-4f;    // 2x split-bf16 err (~4e-5) + 8-bit pack err (~6e-5)
constexpr int RCAP = 32768;

typedef __attribute__((ext_vector_type(8))) short short8;
typedef __attribute__((ext_vector_type(4))) float f32x4;

__device__ __forceinline__ unsigned short f2bf(float f) {
    unsigned u = __float_as_uint(f);
    return (unsigned short)((u + 0x7fffu + ((u >> 16) & 1u)) >> 16);
}
__device__ __forceinline__ float bf2f(unsigned short u) {
    return __uint_as_float(((unsigned)u) << 16);
}

// ---------------------------------------------------------------------------
// Normalize codebook -> cbn (f32). Init loss / repair counter.
// ---------------------------------------------------------------------------
__global__ void k_cbprep(const float* __restrict__ emb, float* __restrict__ cbn,
                         float* __restrict__ lacc, int* __restrict__ rcnt) {
    int k    = (blockIdx.x << 2) + (threadIdx.x >> 6);
    int lane = threadIdx.x & 63;
    float2 v = ((const float2*)(emb + (size_t)k * Dc))[lane];
    float s = v.x * v.x + v.y * v.y;
    #pragma unroll
    for (int off = 32; off > 0; off >>= 1) s += __shfl_down(s, off);
    s = __shfl(s, 0);
    float inv = 1.f / fmaxf(sqrtf(s), EPSF);
    v.x *= inv; v.y *= inv;
    ((float2*)(cbn + (size_t)k * Dc))[lane] = v;
    if (blockIdx.x == 0 && threadIdx.x == 0) { *lacc = 0.f; *rcnt = 0; }
}

// ---------------------------------------------------------------------------
// Pack normalized codebook into MFMA-operand-order blob:
// group g (16 codes) -> 8 frags (kd 0..3 x {hi,lo}) of 1024B; within a frag,
// 16B slot l = q*16 + (k&15) holds bf16 of dims (kd*4+q)*8 .. +7 of code k.
// A wave reading  blob + g*8192 + f*1024 + lane*16  gets its exact B-frag,
// lane-linear (conflict-free everywhere).
// ---------------------------------------------------------------------------
__global__ void k_blob(const float* __restrict__ cbn, char* __restrict__ blob) {
    int id = blockIdx.x * 256 + threadIdx.x;   // 65536 = 4096 codes x 16 chunks
    int k = id >> 4, c = id & 15;
    int kd = c >> 2, q = c & 3;
    const float* src = cbn + (size_t)k * Dc + c * 8;
    float4 a = *(const float4*)src, b = *(const float4*)(src + 4);
    float v[8] = {a.x, a.y, a.z, a.w, b.x, b.y, b.z, b.w};
    short8 hh, ll;
    #pragma unroll
    for (int j = 0; j < 8; ++j) {
        unsigned short hb = f2bf(v[j]);
        hh[j] = (short)hb;
        ll[j] = (short)f2bf(v[j] - bf2f(hb));
    }
    size_t base = (size_t)(k >> 4) * 8192 + (size_t)(q * 16 + (k & 15)) * 16;
    *(short8*)(blob + base + (kd * 2 + 0) * 1024) = hh;
    *(short8*)(blob + base + (kd * 2 + 1) * 1024) = ll;
}

// ---------------------------------------------------------------------------
// MFMA argmax. Block = 512 thr / 8 waves = (4 rowsets x 2 codesets),
// 256 rows/block, grid 256 (fully resident). Per wave: 64 rows in A regs
// (rt=4, hi/lo split), tile = 32 codes (16 per codeset), double-buffered
// 2x16KB LDS, every LDS/global access lane-linear. 8-bit packed fold.
// ---------------------------------------------------------------------------
__global__ __launch_bounds__(512, 2)
void k_argmax(const float* __restrict__ x, const char* __restrict__ blob,
              float* __restrict__ invn, int* __restrict__ idx_out,
              float* __restrict__ lossacc, int* __restrict__ rcnt,
              int* __restrict__ rlist) {
    __shared__ __align__(16) char smem[33280];
    float* xt   = (float*)smem;              // [64][129] (preamble overlay)
    float* invl = (float*)(smem + 33024);    // [64]

    const int tid  = threadIdx.x;
    const int w    = tid >> 6;
    const int lane = tid & 63;
    const int m16  = lane & 15;
    const int quad = lane >> 4;
    const int rs   = w >> 1;      // rowset 0..3 (64 rows each)
    const int cs   = w & 1;       // codeset 0/1 (16 codes per tile)
    const int n0   = blockIdx.x * 256;
    const int bI   = n0 >> 12;
    const int l0   = n0 & (Lc - 1);
    const float* xb = x + (size_t)bI * Dc * Lc;

    // ---- tile-0 prefetch: this wave's share of group g=cs (2KB, lane-linear)
    const char* pb = blob + cs * 8192 + rs * 2048 + lane * 16;
    int4 pf[2];
    pf[0] = *(const int4*)pb;
    pf[1] = *(const int4*)(pb + 1024);

    // ---- preamble: 4 halves of 64 rows: transpose, normalize, build A frags
    short8 ah[4][4], al[4][4];
    for (int h = 0; h < 4; ++h) {
        __syncthreads();
        #pragma unroll
        for (int j = 0; j < 4; ++j) {
            int fl = tid + j * 512;              // 0..2047
            int d = fl >> 4, lq = fl & 15;
            float4 v = *(const float4*)(xb + (size_t)d * Lc + l0 + h * 64 + lq * 4);
            xt[(lq * 4 + 0) * 129 + d] = v.x;
            xt[(lq * 4 + 1) * 129 + d] = v.y;
            xt[(lq * 4 + 2) * 129 + d] = v.z;
            xt[(lq * 4 + 3) * 129 + d] = v.w;
        }
        __syncthreads();
        {   // row norms, 8 threads/row
            int row = tid >> 3, q = tid & 7;
            float s = 0.f;
            #pragma unroll
            for (int j = 0; j < 16; ++j) { float t = xt[row * 129 + q * 16 + j]; s += t * t; }
            s += __shfl_down(s, 1); s += __shfl_down(s, 2); s += __shfl_down(s, 4);
            if (q == 0) {
                float inv = 1.f / fmaxf(sqrtf(s), EPSF);
                invl[row] = inv;
                invn[n0 + h * 64 + row] = inv;
            }
        }
        __syncthreads();
        if (rs == h) {   // both cs-waves of this rowset build the frags
            #pragma unroll
            for (int rt = 0; rt < 4; ++rt) {
                int rl = rt * 16 + m16;          // A layout: m = lane&15
                float inv = invl[rl];
                #pragma unroll
                for (int kd = 0; kd < 4; ++kd) {
                    int dof = kd * 32 + quad * 8;   // k = quad*8 + j
                    short8 hhv, llv;
                    #pragma unroll
                    for (int j = 0; j < 8; ++j) {
                        float xn = xt[rl * 129 + dof + j] * inv;
                        unsigned short hb = f2bf(xn);
                        hhv[j] = (short)hb;
                        llv[j] = (short)f2bf(xn - bf2f(hb));
                    }
                    ah[rt][kd] = hhv; al[rt][kd] = llv;
                }
            }
        }
    }
    __syncthreads();   // xt dead; double-buffer owns smem[0..32768)

    // ---- K loop: 128 tiles of 32 codes (16 per codeset) ----
    const f32x4 fz = {0.f, 0.f, 0.f, 0.f};
    float Bb[16], Ss[16];
    #pragma unroll
    for (int i = 0; i < 16; ++i) { Bb[i] = -3.0e38f; Ss[i] = -3.0e38f; }
    unsigned kc8 = (unsigned)cs;     // packed tag = code>>4 = t*2+cs

    char* wbase = smem + cs * 8192 + rs * 2048 + lane * 16;
    const char* rbase = smem + cs * 8192 + lane * 16;

    for (int tt = 0; tt < 64; ++tt) {
        #pragma unroll
        for (int half = 0; half < 2; ++half) {
            const int t = tt * 2 + half;
            const int boff = half * 16384;
            // stage prefetched share (lane-linear writes)
            *(int4*)(wbase + boff)        = pf[0];
            *(int4*)(wbase + boff + 1024) = pf[1];
            __syncthreads();
            if (t < 127) {   // prefetch tile t+1 (lane-linear global)
                const char* p = pb + (size_t)(t + 1) * 16384;
                pf[0] = *(const int4*)p;
                pf[1] = *(const int4*)(p + 1024);
            }
            // MFMA: 4 kd-chunks x 3 passes x 4 row-tiles
            f32x4 acc[4];
            const char* rb = rbase + boff;
            #pragma unroll
            for (int kd = 0; kd < 4; ++kd) {
                short8 bh = *(const short8*)(rb + kd * 2048);
                short8 bl = *(const short8*)(rb + kd * 2048 + 1024);
                #pragma unroll
                for (int rt = 0; rt < 4; ++rt)
                    acc[rt] = __builtin_amdgcn_mfma_f32_16x16x32_bf16(
                        ah[rt][kd], bh, (kd == 0) ? fz : acc[rt], 0, 0, 0);
                #pragma unroll
                for (int rt = 0; rt < 4; ++rt)
                    acc[rt] = __builtin_amdgcn_mfma_f32_16x16x32_bf16(
                        ah[rt][kd], bl, acc[rt], 0, 0, 0);
                #pragma unroll
                for (int rt = 0; rt < 4; ++rt)
                    acc[rt] = __builtin_amdgcn_mfma_f32_16x16x32_bf16(
                        al[rt][kd], bh, acc[rt], 0, 0, 0);
            }
            // fold: 1 candidate per (slot,lane); 8-bit tag in low mantissa.
            // Ss = max(Ss, min(Bb, p)) is the exact second-best update.
            #pragma unroll
            for (int rt = 0; rt < 4; ++rt)
                #pragma unroll
                for (int rg = 0; rg < 4; ++rg) {
                    int s = rt * 4 + rg;
                    float p = __uint_as_float(
                        (__float_as_uint(acc[rt][rg]) & 0xFFFFFF00u) | kc8);
                    Ss[s] = fmaxf(Ss[s], fminf(Bb[s], p));
                    Bb[s] = fmaxf(Bb[s], p);
                }
            kc8 += 2;
        }
    }

    // ---- epilogue: merge 16 m16-lanes per slot (explicit code) ----
    float mv1[16], mv2[16]; int mk1[16];
    #pragma unroll
    for (int s = 0; s < 16; ++s) {
        float v1 = Bb[s], v2 = Ss[s];
        int k1 = (int)(((__float_as_uint(v1) & 0xFFu) << 4) | (unsigned)m16);
        #pragma unroll
        for (int off = 1; off < 16; off <<= 1) {
            float ov1 = __shfl_xor(v1, off);
            float ov2 = __shfl_xor(v2, off);
            int   ok1 = __shfl_xor(k1, off);
            bool gt = ov1 > v1, eq = ov1 == v1;
            v2 = gt ? fmaxf(ov2, v1) : fmaxf(v2, ov1);
            v1 = gt ? ov1 : v1;
            k1 = gt ? ok1 : (eq ? min(k1, ok1) : k1);
        }
        mv1[s] = v1; mv2[s] = v2; mk1[s] = k1;
    }
    // cross-codeset merge via LDS: [256 rows][2 cs]
    float* Ev = (float*)smem;                // 2048 B
    float* Sv = (float*)(smem + 2048);
    int*   Kv = (int*)(smem + 4096);
    float* bsum = (float*)(smem + 6144);
    __syncthreads();
    if (tid == 0) *bsum = 0.f;
    if (m16 == 0) {
        #pragma unroll
        for (int s = 0; s < 16; ++s) {
            int rt = s >> 2, rg = s & 3;
            int row = rs * 64 + rt * 16 + quad * 4 + rg;   // C row = quad*4+reg
            Ev[row * 2 + cs] = mv1[s];
            Sv[row * 2 + cs] = mv2[s];
            Kv[row * 2 + cs] = mk1[s];
        }
    }
    __syncthreads();
    if (tid < 256) {
        float v1 = Ev[tid * 2], v2 = Sv[tid * 2];
        int   k1 = Kv[tid * 2];
        float ov1 = Ev[tid * 2 + 1], ov2 = Sv[tid * 2 + 1];
        int   ok1 = Kv[tid * 2 + 1];
        bool gt = ov1 > v1, eq = ov1 == v1;
        v2 = gt ? fmaxf(ov2, v1) : fmaxf(v2, ov1);
        v1 = gt ? ov1 : v1;
        k1 = gt ? ok1 : (eq ? min(k1, ok1) : k1);
        int n = n0 + tid;
        idx_out[n] = k1;
        atomicAdd(bsum, v1);
        if (v1 - v2 < TAU) {
            int pos = atomicAdd(rcnt, 1);
            if (pos < RCAP) rlist[pos] = n;
        }
    }
    __syncthreads();
    if (tid == 0) atomicAdd(lossacc, *bsum);
}

// ---------------------------------------------------------------------------
// Exact fp32 re-argmax. One block per flagged query (no chunk split, no
// cross-XCD re-gather); writes idx directly. Grid-stride over the list.
// ---------------------------------------------------------------------------
__global__ __launch_bounds__(256)
void k_repair(const float* __restrict__ x, const float* __restrict__ invn,
              const float* __restrict__ cbn, int* __restrict__ idx,
              const int* __restrict__ rcnt, const int* __restrict__ rlist) {
    __shared__ float xs[128];
    __shared__ unsigned long long red[4];
    int cnt = *rcnt; if (cnt > RCAP) cnt = RCAP;
    const int tid = threadIdx.x;
    for (int e = blockIdx.x; e < cnt; e += gridDim.x) {
        int n = rlist[e]; int b = n >> 12; int l = n & (Lc - 1);
        __syncthreads();
        if (tid < 128)
            xs[tid] = x[(size_t)b * Dc * Lc + (size_t)tid * Lc + l] * invn[n];
        __syncthreads();
        const float4* xv = (const float4*)xs;
        float best = -3.0e38f; int bk = 0;
        #pragma unroll 1
        for (int i = 0; i < 16; ++i) {
            int k = tid * 16 + i;                 // ascending: '> ' keeps min k
            const float4* cr = (const float4*)(cbn + (size_t)k * Dc);
            float s = 0.f;
            #pragma unroll
            for (int j = 0; j < 32; ++j) {
                float4 c = cr[j], xx = xv[j];
                s = fmaf(c.x, xx.x, s); s = fmaf(c.y, xx.y, s);
                s = fmaf(c.z, xx.z, s); s = fmaf(c.w, xx.w, s);
            }
            if (s > best) { best = s; bk = k; }
        }
        unsigned kb = __float_as_uint(best);
        kb = (kb & 0x80000000u) ? ~kb : (kb | 0x80000000u);
        unsigned long long pk =
            ((unsigned long long)kb << 32) | (unsigned)(0xFFFFFFFFu - (unsigned)bk);
        #pragma unroll
        for (int off = 32; off >= 1; off >>= 1) {
            unsigned long long o = __shfl_xor(pk, off);
            pk = (o > pk) ? o : pk;
        }
        if ((tid & 63) == 0) red[tid >> 6] = pk;
        __syncthreads();
        if (tid == 0) {
            unsigned long long m = red[0];
            for (int i = 1; i < 4; ++i) if (red[i] > m) m = red[i];
            idx[n] = (int)(0xFFFFFFFFu - (unsigned)(m & 0xFFFFFFFFull));
        }
    }
}

// ---------------------------------------------------------------------------
__global__ void k_gather(const float* __restrict__ cbn, const int* __restrict__ idx,
                         float* __restrict__ out) {
    __shared__ int sidx[64];
    int n0 = blockIdx.x << 6;
    int b  = n0 >> 12;
    int l0 = n0 & (Lc - 1);
    if (threadIdx.x < 64) sidx[threadIdx.x] = idx[n0 + threadIdx.x];
    __syncthreads();
    int t = threadIdx.x;
    #pragma unroll
    for (int i = 0; i < 32; ++i) {
        int p = t + (i << 8);
        int d = p >> 6;
        int l = p & 63;
        out[(size_t)b * Dc * Lc + (size_t)d * Lc + l0 + l] = cbn[(size_t)sidx[l] * Dc + d];
    }
}

__global__ void k_loss(const float* __restrict__ lacc, float* __restrict__ oloss) {
    *oloss = 2.0f - 2.0f * (*lacc) / (float)Nc;
}

// ---------------------------------------------------------------------------
extern "C" void kernel_launch(void* const* d_in, const int* in_sizes, int n_in,
                              void* d_out, int out_size, void* d_ws, size_t ws_size,
                              hipStream_t stream) {
    const float* x   = (const float*)d_in[0];   // [16][128][4096] fp32
    const float* emb = (const float*)d_in[1];   // [4096][128] fp32
    float* out = (float*)d_out;

    char* ws = (char*)d_ws;
    float* cbn  = (float*)ws;                                  // 2 MB
    char*  blob = ws + (2u << 20);                             // 2 MB
    float* invn = (float*)(ws + (4u << 20));                   // 256 KB
    int*   idx  = (int*)(ws + (4u << 20) + (256u << 10));      // 256 KB
    char*  b5   = ws + (4u << 20) + (512u << 10);
    float* lacc = (float*)b5;
    int*   rcnt = (int*)(b5 + 64);
    int*   rlist= (int*)(b5 + 1024);                           // 128 KB

    k_cbprep<<<Kc / 4,   256, 0, stream>>>(emb, cbn, lacc, rcnt);
    k_blob  <<<Nc / 256, 256, 0, stream>>>(cbn, blob);
    k_argmax<<<Nc / 256, 512, 0, stream>>>(x, blob, invn, idx, lacc, rcnt, rlist);
    k_repair<<<1024,     256, 0, stream>>>(x, invn, cbn, idx, rcnt, rlist);
    k_gather<<<Nc / 64,  256, 0, stream>>>(cbn, idx, out);
    k_loss  <<<1, 1,     0, stream>>>(lacc, out + (size_t)Bc * Dc * Lc);
}